// Round 8
// baseline (214.411 us; speedup 1.0000x reference)
//
#include <hip/hip_runtime.h>

#define BB 16
#define C 192
#define COUT 384
#define H 64
#define W 64
#define HW (H * W)
#define KK 9
#define OFFC 18
#define WROWS 14  // sample_dw staged window rows: [h0-3, h0+11)

typedef __attribute__((ext_vector_type(8))) short short8;
typedef __attribute__((ext_vector_type(4))) float f32x4;

// round-to-nearest-even f32 -> bf16 bits
static __device__ inline unsigned short f2bf(float f) {
  union { float f; unsigned u; } v;
  v.f = f;
  unsigned r = v.u + 0x7FFF + ((v.u >> 16) & 1);
  return (unsigned short)(r >> 16);
}

static __device__ inline short8 ld_frag8(const unsigned* p) {
  union { unsigned u[4]; short8 s; } v;
  uint2 a = *(const uint2*)p;
  uint2 b = *(const uint2*)(p + 2);
  v.u[0] = a.x; v.u[1] = a.y; v.u[2] = b.x; v.u[3] = b.y;
  return v.s;
}

// ---------------------------------------------------------------------------
// Prep: wA[k][o(32, zero-padded)][c(192)] bf16 from w_off[o][c][k] f32
// ---------------------------------------------------------------------------
__global__ __launch_bounds__(256) void prep_woff(
    const float* __restrict__ w_off, unsigned short* __restrict__ wA) {
  int idx = blockIdx.x * 256 + threadIdx.x;
  if (idx >= 9 * 32 * C) return;
  int k = idx / (32 * C);
  int rem = idx % (32 * C);
  int o = rem / C;
  int c = rem % C;
  float v = (o < OFFC) ? w_off[((size_t)o * C + c) * KK + k] : 0.f;
  wA[idx] = f2bf(v);
}

// ---------------------------------------------------------------------------
// Prep: wPW[o][cd] packed bf16 c-pairs from w_pw[o][c] f32  (384 x 96 dwords)
// ---------------------------------------------------------------------------
__global__ __launch_bounds__(256) void prep_wpw(
    const float* __restrict__ w_pw, unsigned* __restrict__ wPW) {
  int idx = blockIdx.x * 256 + threadIdx.x;
  if (idx >= COUT * (C / 2)) return;
  float2 v = *(const float2*)(w_pw + (size_t)idx * 2);
  wPW[idx] = ((unsigned)f2bf(v.y) << 16) | (unsigned)f2bf(v.x);
}

// ---------------------------------------------------------------------------
// Kernel A: offset conv via bf16 MFMA, K-split over 6 chunk-blocks [unchanged]
// ---------------------------------------------------------------------------
__global__ __launch_bounds__(256) void offset_mfma(
    const float* __restrict__ x, const unsigned short* __restrict__ wA,
    const float* __restrict__ b_off, float* __restrict__ offs) {
  int blk = blockIdx.x;
  int chunk = blk % 6;
  int stripe = (blk / 6) & 15;
  int b = blk / 96;
  int h0 = stripe * 4;
  int c0 = chunk * 32;
  int tid = threadIdx.x;
  int lane = tid & 63;
  int wv = tid >> 6;
  int lpx = lane & 15;
  int lkg = lane >> 4;

  __shared__ __align__(16) unsigned short xlds[6 * 68 * 40];  // 32640 B

  for (int i = tid; i < 6 * 2 * 16; i += 256) {
    int rr = i >> 5;
    int side = (i >> 4) & 1;
    int cd = i & 15;
    int m = side ? 65 : 0;
    ((unsigned*)xlds)[(rr * 68 + m) * 20 + cd] = 0u;
  }

  const float* xb = x + (size_t)b * C * HW;
#pragma unroll
  for (int t = 0; t < 24; ++t) {
    int i = t * 256 + tid;
    int cc2 = i / 384;
    int rem = i % 384;
    int rr = rem >> 6;
    int col = rem & 63;
    int ly = h0 + rr - 1;
    float a0 = 0.f, a1 = 0.f;
    if (ly >= 0 && ly < H) {
      const float* xp = xb + (size_t)(c0 + 2 * cc2) * HW + ly * W + col;
      a0 = xp[0];
      a1 = xp[HW];
    }
    unsigned pack = ((unsigned)f2bf(a1) << 16) | (unsigned)f2bf(a0);
    ((unsigned*)xlds)[(rr * 68 + col + 1) * 20 + cc2] = pack;
  }

  short8 af[9][2];
#pragma unroll
  for (int k = 0; k < 9; ++k)
#pragma unroll
    for (int m = 0; m < 2; ++m)
      af[k][m] = *(const short8*)(wA + (size_t)(k * 32 + m * 16 + lpx) * C +
                                  c0 + lkg * 8);

  f32x4 acc[4][2];
#pragma unroll
  for (int nt = 0; nt < 4; ++nt)
#pragma unroll
    for (int m = 0; m < 2; ++m) acc[nt][m] = (f32x4){0.f, 0.f, 0.f, 0.f};

  __syncthreads();

#pragma unroll
  for (int nt = 0; nt < 4; ++nt) {
#pragma unroll
    for (int k = 0; k < 9; ++k) {
      int ki = k / 3, kj = k % 3;
      short8 bf =
          *(const short8*)&xlds[((wv + ki) * 68 + nt * 16 + lpx + kj) * 40 +
                                lkg * 8];
      acc[nt][0] = __builtin_amdgcn_mfma_f32_16x16x32_bf16(af[k][0], bf,
                                                           acc[nt][0], 0, 0, 0);
      acc[nt][1] = __builtin_amdgcn_mfma_f32_16x16x32_bf16(af[k][1], bf,
                                                           acc[nt][1], 0, 0, 0);
    }
  }

  int h = h0 + wv;
#pragma unroll
  for (int nt = 0; nt < 4; ++nt) {
    int col = nt * 16 + lpx;
#pragma unroll
    for (int j = 0; j < 4; ++j) {
      int o = lkg * 4 + j;
      float v = acc[nt][0][j] + ((chunk == 0) ? b_off[o] : 0.f);
      atomicAdd(&offs[((size_t)b * OFFC + o) * HW + h * W + col], v);
    }
    if (lkg == 0) {
#pragma unroll
      for (int j = 0; j < 2; ++j) {
        int o2 = 16 + j;
        float v = acc[nt][1][j] + ((chunk == 0) ? b_off[o2] : 0.f);
        atomicAdd(&offs[((size_t)b * OFFC + o2) * HW + h * W + col], v);
      }
    }
  }
}

// ---------------------------------------------------------------------------
// Kernel B: bilinear sample + depthwise -> dwp[B][96][HW] packed bf16 c-pairs
// v3: float4 LDS cells (4 f32 channels, no unpack), 14-row window,
// double-buffered staging (1 barrier/quad). Out-of-window taps (>4.8 sigma)
// use direct global gathers for full correctness.
// ---------------------------------------------------------------------------
__global__ __launch_bounds__(512) void sample_dw(
    const float* __restrict__ x, const float* __restrict__ offs,
    const float* __restrict__ w_dw, unsigned* __restrict__ dwp) {
  int blk = blockIdx.x;
  int csplit = blk & 7;
  int rowtile = (blk >> 3) & 7;
  int b = blk >> 6;
  int tid = threadIdx.x;
  int r = tid >> 6;
  int w = tid & 63;
  int h = rowtile * 8 + r;
  int lo = rowtile * 8 - 3;  // window rows [lo, lo+WROWS)

  __shared__ float4 S[2][WROWS * 68];  // 2 x 15232 B

  // zero pad columns m in {0,65,66,67} for both buffers (stores only hit 1..64)
  for (int i = tid; i < 2 * WROWS * 4; i += 512) {
    int bf = i / (WROWS * 4);
    int rem = i % (WROWS * 4);
    int rr = rem >> 2;
    int p = rem & 3;
    int m = (p == 0) ? 0 : 64 + p;
    S[bf][rr * 68 + m] = make_float4(0.f, 0.f, 0.f, 0.f);
  }

  // per-pixel tap setup (channel-independent)
  const float* ob = offs + (size_t)b * OFFC * HW + (size_t)h * W + w;
  int idxA[KK], idxB[KK], gpk[KK];
  float wt[KK][4];
  int okmask = 0;
#pragma unroll
  for (int k = 0; k < KK; ++k) {
    int ki = k / 3, kj = k % 3;
    float oy = ob[(size_t)(2 * k) * HW];
    float ox = ob[(size_t)(2 * k + 1) * HW];
    float py = (float)(h - 1 + ki) + oy;
    float px = (float)(w - 1 + kj) + ox;
    float y0f = floorf(py), x0f = floorf(px);
    float dy = py - y0f, dx = px - x0f;
    int y0 = (int)y0f, x0 = (int)x0f;
    int y1 = y0 + 1, x1 = x0 + 1;
    float vy0 = (y0 >= 0 && y0 < H) ? 1.f : 0.f;
    float vy1 = (y1 >= 0 && y1 < H) ? 1.f : 0.f;
    float vx0 = (x0 >= 0 && x0 < W) ? 1.f : 0.f;
    float vx1 = (x1 >= 0 && x1 < W) ? 1.f : 0.f;
    int y0c = min(max(y0, 0), H - 1);
    int y1c = min(max(y1, 0), H - 1);
    int xc0 = min(max(x0, 0), W - 1);
    int xc1 = min(max(x1, 0), W - 1);
    int xm = min(max(x0, -1), 65) + 1;  // plane cols (xm, xm+1)
    int wy0 = y0c - lo, wy1 = y1c - lo;
    bool ok = ((unsigned)wy0 < WROWS) && ((unsigned)wy1 < WROWS);
    okmask |= ((int)ok) << k;
    idxA[k] = wy0 * 68 + xm;
    idxB[k] = wy1 * 68 + xm;
    gpk[k] = y0c | (y1c << 6) | (xc0 << 12) | (xc1 << 18);
    wt[k][0] = (1.f - dy) * (1.f - dx) * vy0 * vx0;
    wt[k][1] = (1.f - dy) * dx * vy0 * vx1;
    wt[k][2] = dy * (1.f - dx) * vy1 * vx0;
    wt[k][3] = dy * dx * vy1 * vx1;
  }

  const int c0 = csplit * 24;
  const float* xq0 = x + ((size_t)b * C + c0) * HW;

  // stage quad 0 into buffer 0
  for (int i = tid; i < WROWS * 64; i += 512) {
    int rr = i >> 6;
    int col = i & 63;
    int ly = lo + rr;
    float4 v = make_float4(0.f, 0.f, 0.f, 0.f);
    if (ly >= 0 && ly < H) {
      const float* xp = xq0 + (size_t)ly * W + col;
      v.x = xp[0];
      v.y = xp[HW];
      v.z = xp[2 * HW];
      v.w = xp[3 * HW];
    }
    S[0][rr * 68 + col + 1] = v;
  }
  __syncthreads();

  for (int q = 0; q < 6; ++q) {
    const float4* Sb = S[q & 1];
    // prefetch next quad into the other buffer (overlaps with tap loop)
    if (q < 5) {
      const float* xq = xq0 + (size_t)((q + 1) * 4) * HW;
      float4* Sw = S[(q + 1) & 1];
      for (int i = tid; i < WROWS * 64; i += 512) {
        int rr = i >> 6;
        int col = i & 63;
        int ly = lo + rr;
        float4 v = make_float4(0.f, 0.f, 0.f, 0.f);
        if (ly >= 0 && ly < H) {
          const float* xp = xq + (size_t)ly * W + col;
          v.x = xp[0];
          v.y = xp[HW];
          v.z = xp[2 * HW];
          v.w = xp[3 * HW];
        }
        Sw[rr * 68 + col + 1] = v;
      }
    }

    int cq = c0 + q * 4;
    const float* xq = xq0 + (size_t)(q * 4) * HW;   // for fallback
    const float* wd = w_dw + (size_t)cq * KK;       // block-uniform -> s_load
    float acc0 = 0.f, acc1 = 0.f, acc2 = 0.f, acc3 = 0.f;
#pragma unroll
    for (int k = 0; k < KK; ++k) {
      float w0 = wt[k][0], w1 = wt[k][1], w2 = wt[k][2], w3 = wt[k][3];
      float t0, t1, t2, t3;
      if (__builtin_expect((okmask >> k) & 1, 1)) {
        float4 u00 = Sb[idxA[k]];
        float4 u01 = Sb[idxA[k] + 1];
        float4 u10 = Sb[idxB[k]];
        float4 u11 = Sb[idxB[k] + 1];
        t0 = fmaf(w3, u11.x, fmaf(w2, u10.x, fmaf(w1, u01.x, w0 * u00.x)));
        t1 = fmaf(w3, u11.y, fmaf(w2, u10.y, fmaf(w1, u01.y, w0 * u00.y)));
        t2 = fmaf(w3, u11.z, fmaf(w2, u10.z, fmaf(w1, u01.z, w0 * u00.z)));
        t3 = fmaf(w3, u11.w, fmaf(w2, u10.w, fmaf(w1, u01.w, w0 * u00.w)));
      } else {  // out-of-window fallback: direct global gather (f32)
        int g = gpk[k];
        int a00 = (g & 63) * W + ((g >> 12) & 63);
        int a01 = (g & 63) * W + ((g >> 18) & 63);
        int a10 = ((g >> 6) & 63) * W + ((g >> 12) & 63);
        int a11 = ((g >> 6) & 63) * W + ((g >> 18) & 63);
        const float* p0 = xq;
        const float* p1 = xq + HW;
        const float* p2 = xq + 2 * HW;
        const float* p3 = xq + 3 * HW;
        t0 = fmaf(w3, p0[a11], fmaf(w2, p0[a10], fmaf(w1, p0[a01], w0 * p0[a00])));
        t1 = fmaf(w3, p1[a11], fmaf(w2, p1[a10], fmaf(w1, p1[a01], w0 * p1[a00])));
        t2 = fmaf(w3, p2[a11], fmaf(w2, p2[a10], fmaf(w1, p2[a01], w0 * p2[a00])));
        t3 = fmaf(w3, p3[a11], fmaf(w2, p3[a10], fmaf(w1, p3[a01], w0 * p3[a00])));
      }
      acc0 = fmaf(wd[k], t0, acc0);
      acc1 = fmaf(wd[KK + k], t1, acc1);
      acc2 = fmaf(wd[2 * KK + k], t2, acc2);
      acc3 = fmaf(wd[3 * KK + k], t3, acc3);
    }
    size_t obase = ((size_t)b * 96 + (cq >> 1)) * HW + (size_t)h * W + w;
    dwp[obase] = ((unsigned)f2bf(acc1) << 16) | (unsigned)f2bf(acc0);
    dwp[obase + HW] = ((unsigned)f2bf(acc3) << 16) | (unsigned)f2bf(acc2);
    __syncthreads();
  }
}

// ---------------------------------------------------------------------------
// Kernel C: pointwise 1x1 conv via bf16 MFMA  [unchanged]
// ---------------------------------------------------------------------------
__global__ __launch_bounds__(256) void pointwise_mfma(
    const unsigned* __restrict__ dwp, const unsigned* __restrict__ wPW,
    float* __restrict__ out) {
  int blk = blockIdx.x;
  int nt = blk & 63;
  int mt = (blk >> 6) % 3;
  int b = blk / 192;
  int n0 = nt * 64;
  int m0 = mt * 128;
  int tid = threadIdx.x;
  int lane = tid & 63;
  int wv = tid >> 6;
  int wm = wv >> 1;
  int wn = wv & 1;
  int lpx = lane & 15;
  int lkg = lane >> 4;

  __shared__ __align__(16) unsigned sA[128 * 22];
  __shared__ __align__(16) unsigned sB[64 * 22];

  f32x4 acc[4][2];
#pragma unroll
  for (int mf = 0; mf < 4; ++mf)
#pragma unroll
    for (int nf = 0; nf < 2; ++nf) acc[mf][nf] = (f32x4){0.f, 0.f, 0.f, 0.f};

  const unsigned* dwb = dwp + (size_t)b * 96 * HW + n0;

  for (int chunk = 0; chunk < 6; ++chunk) {
    int kp0 = chunk * 16;
    __syncthreads();
#pragma unroll
    for (int t = 0; t < 8; ++t) {
      int i = t * 256 + tid;
      int m = i >> 4;
      int cd = i & 15;
      sA[m * 22 + cd] = wPW[(size_t)(m0 + m) * 96 + kp0 + cd];
    }
#pragma unroll
    for (int t = 0; t < 4; ++t) {
      int i = t * 256 + tid;
      int kp = i >> 6;
      int px = i & 63;
      sB[px * 22 + kp] = dwb[(size_t)(kp0 + kp) * HW + px];
    }
    __syncthreads();

    short8 af[4];
#pragma unroll
    for (int mf = 0; mf < 4; ++mf) {
      int m = wm * 64 + mf * 16 + lpx;
      af[mf] = ld_frag8(&sA[m * 22 + lkg * 4]);
    }
    short8 bf[2];
#pragma unroll
    for (int nf = 0; nf < 2; ++nf) {
      int px = wn * 32 + nf * 16 + lpx;
      bf[nf] = ld_frag8(&sB[px * 22 + lkg * 4]);
    }
#pragma unroll
    for (int mf = 0; mf < 4; ++mf)
#pragma unroll
      for (int nf = 0; nf < 2; ++nf)
        acc[mf][nf] = __builtin_amdgcn_mfma_f32_16x16x32_bf16(
            af[mf], bf[nf], acc[mf][nf], 0, 0, 0);
  }

#pragma unroll
  for (int mf = 0; mf < 4; ++mf) {
#pragma unroll
    for (int nf = 0; nf < 2; ++nf) {
      int px = n0 + wn * 32 + nf * 16 + lpx;
#pragma unroll
      for (int j = 0; j < 4; ++j) {
        int o = m0 + wm * 64 + mf * 16 + lkg * 4 + j;
        out[((size_t)b * COUT + o) * HW + px] = acc[mf][nf][j];
      }
    }
  }
}

// ---------------------------------------------------------------------------
extern "C" void kernel_launch(void* const* d_in, const int* in_sizes, int n_in,
                              void* d_out, int out_size, void* d_ws,
                              size_t ws_size, hipStream_t stream) {
  const float* x = (const float*)d_in[0];
  const float* w_off = (const float*)d_in[1];
  const float* b_off = (const float*)d_in[2];
  const float* w_dw = (const float*)d_in[3];
  const float* w_pw = (const float*)d_in[4];
  float* out = (float*)d_out;

  char* ws = (char*)d_ws;
  float* offs = (float*)ws;                       // 4.72 MB
  unsigned* dwp = (unsigned*)(ws + 4718592);      // 25.17 MB
  unsigned short* wA = (unsigned short*)(ws + 4718592 + 25165824);  // 110 KB
  unsigned* wPW = (unsigned*)(ws + 4718592 + 25165824 + 110592);    // 147 KB

  hipMemsetAsync(offs, 0, (size_t)BB * OFFC * HW * sizeof(float), stream);
  prep_woff<<<(9 * 32 * C + 255) / 256, 256, 0, stream>>>(w_off, wA);
  prep_wpw<<<(COUT * (C / 2) + 255) / 256, 256, 0, stream>>>(w_pw, wPW);
  offset_mfma<<<BB * 16 * 6, 256, 0, stream>>>(x, wA, b_off, offs);
  sample_dw<<<BB * 8 * 8, 512, 0, stream>>>(x, offs, w_dw, dwp);
  pointwise_mfma<<<BB * 3 * 64, 256, 0, stream>>>(dwp, wPW, out);
}

// Round 9
// 192.545 us; speedup vs baseline: 1.1136x; 1.1136x over previous
//
#include <hip/hip_runtime.h>

#define BB 16
#define C 192
#define COUT 384
#define H 64
#define W 64
#define HW (H * W)
#define KK 9
#define OFFC 18
#define WROWS 22  // sample_dw staged window rows: [h0-7, h0+15)

typedef __attribute__((ext_vector_type(8))) short short8;
typedef __attribute__((ext_vector_type(4))) float f32x4;

// round-to-nearest-even f32 -> bf16 bits
static __device__ inline unsigned short f2bf(float f) {
  union { float f; unsigned u; } v;
  v.f = f;
  unsigned r = v.u + 0x7FFF + ((v.u >> 16) & 1);
  return (unsigned short)(r >> 16);
}

static __device__ inline float blo(unsigned u) {
  union { unsigned u; float f; } v;
  v.u = u << 16;
  return v.f;
}
static __device__ inline float bhi(unsigned u) {
  union { unsigned u; float f; } v;
  v.u = u & 0xFFFF0000u;
  return v.f;
}

static __device__ inline short8 ld_frag8(const unsigned* p) {
  union { unsigned u[4]; short8 s; } v;
  uint2 a = *(const uint2*)p;
  uint2 b = *(const uint2*)(p + 2);
  v.u[0] = a.x; v.u[1] = a.y; v.u[2] = b.x; v.u[3] = b.y;
  return v.s;
}

// ---------------------------------------------------------------------------
// Merged prep: wA[k][o(32 pad)][c] bf16  +  wPW[o][cd] packed bf16 c-pairs
// ---------------------------------------------------------------------------
__global__ __launch_bounds__(256) void prep_weights(
    const float* __restrict__ w_off, const float* __restrict__ w_pw,
    unsigned short* __restrict__ wA, unsigned* __restrict__ wPW) {
  int idx = blockIdx.x * 256 + threadIdx.x;
  if (idx < 9 * 32 * C) {
    int k = idx / (32 * C);
    int rem = idx % (32 * C);
    int o = rem / C;
    int c = rem % C;
    float v = (o < OFFC) ? w_off[((size_t)o * C + c) * KK + k] : 0.f;
    wA[idx] = f2bf(v);
  } else {
    int i2 = idx - 9 * 32 * C;
    if (i2 < COUT * (C / 2)) {
      float2 v = *(const float2*)(w_pw + (size_t)i2 * 2);
      wPW[i2] = ((unsigned)f2bf(v.y) << 16) | (unsigned)f2bf(v.x);
    }
  }
}

// ---------------------------------------------------------------------------
// Kernel A: offset conv via bf16 MFMA, K-split over 6 chunk-blocks [unchanged]
// ---------------------------------------------------------------------------
__global__ __launch_bounds__(256) void offset_mfma(
    const float* __restrict__ x, const unsigned short* __restrict__ wA,
    const float* __restrict__ b_off, float* __restrict__ offs) {
  int blk = blockIdx.x;
  int chunk = blk % 6;
  int stripe = (blk / 6) & 15;
  int b = blk / 96;
  int h0 = stripe * 4;
  int c0 = chunk * 32;
  int tid = threadIdx.x;
  int lane = tid & 63;
  int wv = tid >> 6;
  int lpx = lane & 15;
  int lkg = lane >> 4;

  __shared__ __align__(16) unsigned short xlds[6 * 68 * 40];  // 32640 B

  for (int i = tid; i < 6 * 2 * 16; i += 256) {
    int rr = i >> 5;
    int side = (i >> 4) & 1;
    int cd = i & 15;
    int m = side ? 65 : 0;
    ((unsigned*)xlds)[(rr * 68 + m) * 20 + cd] = 0u;
  }

  const float* xb = x + (size_t)b * C * HW;
#pragma unroll
  for (int t = 0; t < 24; ++t) {
    int i = t * 256 + tid;
    int cc2 = i / 384;
    int rem = i % 384;
    int rr = rem >> 6;
    int col = rem & 63;
    int ly = h0 + rr - 1;
    float a0 = 0.f, a1 = 0.f;
    if (ly >= 0 && ly < H) {
      const float* xp = xb + (size_t)(c0 + 2 * cc2) * HW + ly * W + col;
      a0 = xp[0];
      a1 = xp[HW];
    }
    unsigned pack = ((unsigned)f2bf(a1) << 16) | (unsigned)f2bf(a0);
    ((unsigned*)xlds)[(rr * 68 + col + 1) * 20 + cc2] = pack;
  }

  short8 af[9][2];
#pragma unroll
  for (int k = 0; k < 9; ++k)
#pragma unroll
    for (int m = 0; m < 2; ++m)
      af[k][m] = *(const short8*)(wA + (size_t)(k * 32 + m * 16 + lpx) * C +
                                  c0 + lkg * 8);

  f32x4 acc[4][2];
#pragma unroll
  for (int nt = 0; nt < 4; ++nt)
#pragma unroll
    for (int m = 0; m < 2; ++m) acc[nt][m] = (f32x4){0.f, 0.f, 0.f, 0.f};

  __syncthreads();

#pragma unroll
  for (int nt = 0; nt < 4; ++nt) {
#pragma unroll
    for (int k = 0; k < 9; ++k) {
      int ki = k / 3, kj = k % 3;
      short8 bf =
          *(const short8*)&xlds[((wv + ki) * 68 + nt * 16 + lpx + kj) * 40 +
                                lkg * 8];
      acc[nt][0] = __builtin_amdgcn_mfma_f32_16x16x32_bf16(af[k][0], bf,
                                                           acc[nt][0], 0, 0, 0);
      acc[nt][1] = __builtin_amdgcn_mfma_f32_16x16x32_bf16(af[k][1], bf,
                                                           acc[nt][1], 0, 0, 0);
    }
  }

  int h = h0 + wv;
#pragma unroll
  for (int nt = 0; nt < 4; ++nt) {
    int col = nt * 16 + lpx;
#pragma unroll
    for (int j = 0; j < 4; ++j) {
      int o = lkg * 4 + j;
      float v = acc[nt][0][j] + ((chunk == 0) ? b_off[o] : 0.f);
      atomicAdd(&offs[((size_t)b * OFFC + o) * HW + h * W + col], v);
    }
    if (lkg == 0) {
#pragma unroll
      for (int j = 0; j < 2; ++j) {
        int o2 = 16 + j;
        float v = acc[nt][1][j] + ((chunk == 0) ? b_off[o2] : 0.f);
        atomicAdd(&offs[((size_t)b * OFFC + o2) * HW + h * W + col], v);
      }
    }
  }
}

// ---------------------------------------------------------------------------
// Kernel B: bilinear sample + depthwise -> dwp[B][96][HW] packed bf16 c-pairs
// Round-7 structure (uint2 bf16x4 cells, WROWS=22, single buffer — no spill),
// but 16-way channel split: 12 ch = 3 quads per block, grid = B*8*16 = 2048
// blocks. Halves the per-block serial chain so co-resident blocks cover the
// LDS-latency + barrier stalls. Out-of-window taps fall back to global.
// ---------------------------------------------------------------------------
__global__ __launch_bounds__(512) void sample_dw(
    const float* __restrict__ x, const float* __restrict__ offs,
    const float* __restrict__ w_dw, unsigned* __restrict__ dwp) {
  int blk = blockIdx.x;
  int csplit = blk & 15;
  int rowtile = (blk >> 4) & 7;
  int b = blk >> 7;
  int tid = threadIdx.x;
  int r = tid >> 6;
  int w = tid & 63;
  int h = rowtile * 8 + r;
  int lo = rowtile * 8 - 7;  // window rows [lo, lo+WROWS)

  __shared__ uint2 S[WROWS * 68];  // 11968 B

  for (int i = tid; i < WROWS * 4; i += 512) {
    int rr = i >> 2;
    int p = i & 3;
    int m = (p == 0) ? 0 : 64 + p;
    S[rr * 68 + m] = make_uint2(0u, 0u);
  }

  const float* ob = offs + (size_t)b * OFFC * HW + (size_t)h * W + w;
  int idxA[KK], idxB[KK], gpk[KK];
  float wt[KK][4];
  int okmask = 0;
#pragma unroll
  for (int k = 0; k < KK; ++k) {
    int ki = k / 3, kj = k % 3;
    float oy = ob[(size_t)(2 * k) * HW];
    float ox = ob[(size_t)(2 * k + 1) * HW];
    float py = (float)(h - 1 + ki) + oy;
    float px = (float)(w - 1 + kj) + ox;
    float y0f = floorf(py), x0f = floorf(px);
    float dy = py - y0f, dx = px - x0f;
    int y0 = (int)y0f, x0 = (int)x0f;
    int y1 = y0 + 1, x1 = x0 + 1;
    float vy0 = (y0 >= 0 && y0 < H) ? 1.f : 0.f;
    float vy1 = (y1 >= 0 && y1 < H) ? 1.f : 0.f;
    float vx0 = (x0 >= 0 && x0 < W) ? 1.f : 0.f;
    float vx1 = (x1 >= 0 && x1 < W) ? 1.f : 0.f;
    int y0c = min(max(y0, 0), H - 1);
    int y1c = min(max(y1, 0), H - 1);
    int xc0 = min(max(x0, 0), W - 1);
    int xc1 = min(max(x1, 0), W - 1);
    int xm = min(max(x0, -1), 65) + 1;
    int wy0 = y0c - lo, wy1 = y1c - lo;
    bool ok = ((unsigned)wy0 < WROWS) && ((unsigned)wy1 < WROWS);
    okmask |= ((int)ok) << k;
    idxA[k] = wy0 * 68 + xm;
    idxB[k] = wy1 * 68 + xm;
    gpk[k] = y0c | (y1c << 6) | (xc0 << 12) | (xc1 << 18);
    wt[k][0] = (1.f - dy) * (1.f - dx) * vy0 * vx0;
    wt[k][1] = (1.f - dy) * dx * vy0 * vx1;
    wt[k][2] = dy * (1.f - dx) * vy1 * vx0;
    wt[k][3] = dy * dx * vy1 * vx1;
  }

  const int c0 = csplit * 12;
  const float* xq0 = x + ((size_t)b * C + c0) * HW;

  for (int q = 0; q < 3; ++q) {
    const float* xq = xq0 + (size_t)(q * 4) * HW;
    __syncthreads();
    for (int i = tid; i < WROWS * 64; i += 512) {
      int rr = i >> 6;
      int col = i & 63;
      int ly = lo + rr;
      uint2 p = make_uint2(0u, 0u);
      if (ly >= 0 && ly < H) {
        const float* xp = xq + (size_t)ly * W + col;
        p.x = ((unsigned)f2bf(xp[HW]) << 16) | (unsigned)f2bf(xp[0]);
        p.y = ((unsigned)f2bf(xp[3 * HW]) << 16) | (unsigned)f2bf(xp[2 * HW]);
      }
      S[rr * 68 + col + 1] = p;
    }
    __syncthreads();

    int cq = c0 + q * 4;
    const float* wd = w_dw + (size_t)cq * KK;  // block-uniform -> s_load
    float acc0 = 0.f, acc1 = 0.f, acc2 = 0.f, acc3 = 0.f;
#pragma unroll
    for (int k = 0; k < KK; ++k) {
      float w0 = wt[k][0], w1 = wt[k][1], w2 = wt[k][2], w3 = wt[k][3];
      float t0, t1, t2, t3;
      if (__builtin_expect((okmask >> k) & 1, 1)) {
        uint2 u00 = S[idxA[k]], u01 = S[idxA[k] + 1];
        uint2 u10 = S[idxB[k]], u11 = S[idxB[k] + 1];
        t0 = fmaf(w3, blo(u11.x),
             fmaf(w2, blo(u10.x), fmaf(w1, blo(u01.x), w0 * blo(u00.x))));
        t1 = fmaf(w3, bhi(u11.x),
             fmaf(w2, bhi(u10.x), fmaf(w1, bhi(u01.x), w0 * bhi(u00.x))));
        t2 = fmaf(w3, blo(u11.y),
             fmaf(w2, blo(u10.y), fmaf(w1, blo(u01.y), w0 * blo(u00.y))));
        t3 = fmaf(w3, bhi(u11.y),
             fmaf(w2, bhi(u10.y), fmaf(w1, bhi(u01.y), w0 * bhi(u00.y))));
      } else {
        int g = gpk[k];
        int a00 = (g & 63) * W + ((g >> 12) & 63);
        int a01 = (g & 63) * W + ((g >> 18) & 63);
        int a10 = ((g >> 6) & 63) * W + ((g >> 12) & 63);
        int a11 = ((g >> 6) & 63) * W + ((g >> 18) & 63);
        const float* p0 = xq;
        const float* p1 = xq + HW;
        const float* p2 = xq + 2 * HW;
        const float* p3 = xq + 3 * HW;
        t0 = fmaf(w3, p0[a11], fmaf(w2, p0[a10], fmaf(w1, p0[a01], w0 * p0[a00])));
        t1 = fmaf(w3, p1[a11], fmaf(w2, p1[a10], fmaf(w1, p1[a01], w0 * p1[a00])));
        t2 = fmaf(w3, p2[a11], fmaf(w2, p2[a10], fmaf(w1, p2[a01], w0 * p2[a00])));
        t3 = fmaf(w3, p3[a11], fmaf(w2, p3[a10], fmaf(w1, p3[a01], w0 * p3[a00])));
      }
      acc0 = fmaf(wd[k], t0, acc0);
      acc1 = fmaf(wd[KK + k], t1, acc1);
      acc2 = fmaf(wd[2 * KK + k], t2, acc2);
      acc3 = fmaf(wd[3 * KK + k], t3, acc3);
    }
    size_t obase = ((size_t)b * 96 + (cq >> 1)) * HW + (size_t)h * W + w;
    dwp[obase] = ((unsigned)f2bf(acc1) << 16) | (unsigned)f2bf(acc0);
    dwp[obase + HW] = ((unsigned)f2bf(acc3) << 16) | (unsigned)f2bf(acc2);
  }
}

// ---------------------------------------------------------------------------
// Kernel C: pointwise 1x1 conv via bf16 MFMA  [unchanged]
// ---------------------------------------------------------------------------
__global__ __launch_bounds__(256) void pointwise_mfma(
    const unsigned* __restrict__ dwp, const unsigned* __restrict__ wPW,
    float* __restrict__ out) {
  int blk = blockIdx.x;
  int nt = blk & 63;
  int mt = (blk >> 6) % 3;
  int b = blk / 192;
  int n0 = nt * 64;
  int m0 = mt * 128;
  int tid = threadIdx.x;
  int lane = tid & 63;
  int wv = tid >> 6;
  int wm = wv >> 1;
  int wn = wv & 1;
  int lpx = lane & 15;
  int lkg = lane >> 4;

  __shared__ __align__(16) unsigned sA[128 * 22];
  __shared__ __align__(16) unsigned sB[64 * 22];

  f32x4 acc[4][2];
#pragma unroll
  for (int mf = 0; mf < 4; ++mf)
#pragma unroll
    for (int nf = 0; nf < 2; ++nf) acc[mf][nf] = (f32x4){0.f, 0.f, 0.f, 0.f};

  const unsigned* dwb = dwp + (size_t)b * 96 * HW + n0;

  for (int chunk = 0; chunk < 6; ++chunk) {
    int kp0 = chunk * 16;
    __syncthreads();
#pragma unroll
    for (int t = 0; t < 8; ++t) {
      int i = t * 256 + tid;
      int m = i >> 4;
      int cd = i & 15;
      sA[m * 22 + cd] = wPW[(size_t)(m0 + m) * 96 + kp0 + cd];
    }
#pragma unroll
    for (int t = 0; t < 4; ++t) {
      int i = t * 256 + tid;
      int kp = i >> 6;
      int px = i & 63;
      sB[px * 22 + kp] = dwb[(size_t)(kp0 + kp) * HW + px];
    }
    __syncthreads();

    short8 af[4];
#pragma unroll
    for (int mf = 0; mf < 4; ++mf) {
      int m = wm * 64 + mf * 16 + lpx;
      af[mf] = ld_frag8(&sA[m * 22 + lkg * 4]);
    }
    short8 bf[2];
#pragma unroll
    for (int nf = 0; nf < 2; ++nf) {
      int px = wn * 32 + nf * 16 + lpx;
      bf[nf] = ld_frag8(&sB[px * 22 + lkg * 4]);
    }
#pragma unroll
    for (int mf = 0; mf < 4; ++mf)
#pragma unroll
      for (int nf = 0; nf < 2; ++nf)
        acc[mf][nf] = __builtin_amdgcn_mfma_f32_16x16x32_bf16(
            af[mf], bf[nf], acc[mf][nf], 0, 0, 0);
  }

#pragma unroll
  for (int mf = 0; mf < 4; ++mf) {
#pragma unroll
    for (int nf = 0; nf < 2; ++nf) {
      int px = n0 + wn * 32 + nf * 16 + lpx;
#pragma unroll
      for (int j = 0; j < 4; ++j) {
        int o = m0 + wm * 64 + mf * 16 + lkg * 4 + j;
        out[((size_t)b * COUT + o) * HW + px] = acc[mf][nf][j];
      }
    }
  }
}

// ---------------------------------------------------------------------------
extern "C" void kernel_launch(void* const* d_in, const int* in_sizes, int n_in,
                              void* d_out, int out_size, void* d_ws,
                              size_t ws_size, hipStream_t stream) {
  const float* x = (const float*)d_in[0];
  const float* w_off = (const float*)d_in[1];
  const float* b_off = (const float*)d_in[2];
  const float* w_dw = (const float*)d_in[3];
  const float* w_pw = (const float*)d_in[4];
  float* out = (float*)d_out;

  char* ws = (char*)d_ws;
  float* offs = (float*)ws;                       // 4.72 MB
  unsigned* dwp = (unsigned*)(ws + 4718592);      // 25.17 MB
  unsigned short* wA = (unsigned short*)(ws + 4718592 + 25165824);  // 110 KB
  unsigned* wPW = (unsigned*)(ws + 4718592 + 25165824 + 110592);    // 147 KB

  hipMemsetAsync(offs, 0, (size_t)BB * OFFC * HW * sizeof(float), stream);
  prep_weights<<<(9 * 32 * C + COUT * (C / 2) + 255) / 256, 256, 0, stream>>>(
      w_off, w_pw, wA, wPW);
  offset_mfma<<<BB * 16 * 6, 256, 0, stream>>>(x, wA, b_off, offs);
  sample_dw<<<BB * 8 * 16, 512, 0, stream>>>(x, offs, w_dw, dwp);
  pointwise_mfma<<<BB * 3 * 64, 256, 0, stream>>>(dwp, wPW, out);
}

// Round 10
// 152.682 us; speedup vs baseline: 1.4043x; 1.2611x over previous
//
#include <hip/hip_runtime.h>
#include <hip/hip_fp16.h>

#define BB 16
#define C 192
#define COUT 384
#define H 64
#define W 64
#define HW (H * W)
#define KK 9
#define OFFC 18
#define WROWS 22  // sample_dw staged window rows: [h0-7, h0+15)

typedef __attribute__((ext_vector_type(8))) short short8;
typedef __attribute__((ext_vector_type(8))) _Float16 half8;
typedef __attribute__((ext_vector_type(4))) float f32x4;

// round-to-nearest-even f32 -> bf16 bits
static __device__ inline unsigned short f2bf(float f) {
  union { float f; unsigned u; } v;
  v.f = f;
  unsigned r = v.u + 0x7FFF + ((v.u >> 16) & 1);
  return (unsigned short)(r >> 16);
}

union H2U { __half2 h; unsigned u; };

static __device__ inline __half2 bc_h2(unsigned u) {
  H2U v; v.u = u; return v.h;
}
static __device__ inline unsigned h2_bits(__half2 h) {
  H2U v; v.h = h; return v.u;
}

static __device__ inline short8 ld_frag8(const unsigned* p) {
  union { unsigned u[4]; short8 s; } v;
  uint2 a = *(const uint2*)p;
  uint2 b = *(const uint2*)(p + 2);
  v.u[0] = a.x; v.u[1] = a.y; v.u[2] = b.x; v.u[3] = b.y;
  return v.s;
}
static __device__ inline half8 ld_frag8h(const unsigned* p) {
  union { unsigned u[4]; half8 s; } v;
  uint2 a = *(const uint2*)p;
  uint2 b = *(const uint2*)(p + 2);
  v.u[0] = a.x; v.u[1] = a.y; v.u[2] = b.x; v.u[3] = b.y;
  return v.s;
}

// ---------------------------------------------------------------------------
// Merged prep: wA (bf16, offset conv) + wPW (f16 c-pairs) + wdh (f16 dw pairs)
// ---------------------------------------------------------------------------
__global__ __launch_bounds__(256) void prep_weights(
    const float* __restrict__ w_off, const float* __restrict__ w_pw,
    const float* __restrict__ w_dw, unsigned short* __restrict__ wA,
    unsigned* __restrict__ wPW, unsigned* __restrict__ wdh) {
  int idx = blockIdx.x * 256 + threadIdx.x;
  if (idx < 9 * 32 * C) {
    int k = idx / (32 * C);
    int rem = idx % (32 * C);
    int o = rem / C;
    int c = rem % C;
    float v = (o < OFFC) ? w_off[((size_t)o * C + c) * KK + k] : 0.f;
    wA[idx] = f2bf(v);
    return;
  }
  int i2 = idx - 9 * 32 * C;
  if (i2 < COUT * (C / 2)) {
    float2 v = *(const float2*)(w_pw + (size_t)i2 * 2);
    wPW[i2] = h2_bits(__floats2half2_rn(v.x, v.y));
    return;
  }
  int i3 = i2 - COUT * (C / 2);
  if (i3 < (C / 2) * KK) {
    int cp = i3 / KK;
    int k = i3 % KK;
    wdh[i3] = h2_bits(
        __floats2half2_rn(w_dw[(size_t)(2 * cp) * KK + k],
                          w_dw[(size_t)(2 * cp + 1) * KK + k]));
  }
}

// ---------------------------------------------------------------------------
// Kernel A: offset conv via bf16 MFMA, K-split over 6 chunk-blocks [unchanged]
// ---------------------------------------------------------------------------
__global__ __launch_bounds__(256) void offset_mfma(
    const float* __restrict__ x, const unsigned short* __restrict__ wA,
    const float* __restrict__ b_off, float* __restrict__ offs) {
  int blk = blockIdx.x;
  int chunk = blk % 6;
  int stripe = (blk / 6) & 15;
  int b = blk / 96;
  int h0 = stripe * 4;
  int c0 = chunk * 32;
  int tid = threadIdx.x;
  int lane = tid & 63;
  int wv = tid >> 6;
  int lpx = lane & 15;
  int lkg = lane >> 4;

  __shared__ __align__(16) unsigned short xlds[6 * 68 * 40];  // 32640 B

  for (int i = tid; i < 6 * 2 * 16; i += 256) {
    int rr = i >> 5;
    int side = (i >> 4) & 1;
    int cd = i & 15;
    int m = side ? 65 : 0;
    ((unsigned*)xlds)[(rr * 68 + m) * 20 + cd] = 0u;
  }

  const float* xb = x + (size_t)b * C * HW;
#pragma unroll
  for (int t = 0; t < 24; ++t) {
    int i = t * 256 + tid;
    int cc2 = i / 384;
    int rem = i % 384;
    int rr = rem >> 6;
    int col = rem & 63;
    int ly = h0 + rr - 1;
    float a0 = 0.f, a1 = 0.f;
    if (ly >= 0 && ly < H) {
      const float* xp = xb + (size_t)(c0 + 2 * cc2) * HW + ly * W + col;
      a0 = xp[0];
      a1 = xp[HW];
    }
    unsigned pack = ((unsigned)f2bf(a1) << 16) | (unsigned)f2bf(a0);
    ((unsigned*)xlds)[(rr * 68 + col + 1) * 20 + cc2] = pack;
  }

  short8 af[9][2];
#pragma unroll
  for (int k = 0; k < 9; ++k)
#pragma unroll
    for (int m = 0; m < 2; ++m)
      af[k][m] = *(const short8*)(wA + (size_t)(k * 32 + m * 16 + lpx) * C +
                                  c0 + lkg * 8);

  f32x4 acc[4][2];
#pragma unroll
  for (int nt = 0; nt < 4; ++nt)
#pragma unroll
    for (int m = 0; m < 2; ++m) acc[nt][m] = (f32x4){0.f, 0.f, 0.f, 0.f};

  __syncthreads();

#pragma unroll
  for (int nt = 0; nt < 4; ++nt) {
#pragma unroll
    for (int k = 0; k < 9; ++k) {
      int ki = k / 3, kj = k % 3;
      short8 bf =
          *(const short8*)&xlds[((wv + ki) * 68 + nt * 16 + lpx + kj) * 40 +
                                lkg * 8];
      acc[nt][0] = __builtin_amdgcn_mfma_f32_16x16x32_bf16(af[k][0], bf,
                                                           acc[nt][0], 0, 0, 0);
      acc[nt][1] = __builtin_amdgcn_mfma_f32_16x16x32_bf16(af[k][1], bf,
                                                           acc[nt][1], 0, 0, 0);
    }
  }

  int h = h0 + wv;
#pragma unroll
  for (int nt = 0; nt < 4; ++nt) {
    int col = nt * 16 + lpx;
#pragma unroll
    for (int j = 0; j < 4; ++j) {
      int o = lkg * 4 + j;
      float v = acc[nt][0][j] + ((chunk == 0) ? b_off[o] : 0.f);
      atomicAdd(&offs[((size_t)b * OFFC + o) * HW + h * W + col], v);
    }
    if (lkg == 0) {
#pragma unroll
      for (int j = 0; j < 2; ++j) {
        int o2 = 16 + j;
        float v = acc[nt][1][j] + ((chunk == 0) ? b_off[o2] : 0.f);
        atomicAdd(&offs[((size_t)b * OFFC + o2) * HW + h * W + col], v);
      }
    }
  }
}

// ---------------------------------------------------------------------------
// Kernel B: bilinear sample + depthwise -> dwp[B][96][HW] packed f16 c-pairs
// R7 structure (uint2 cells, WROWS=22, single buffer, 8-way split, 1024 blk)
// but f16 packed math: per tap per 4ch = 4 ds_read_b64 + 10 v_pk_fma_f16
// (no unpack, no output packing). w_dw pre-packed to half2 (s_load).
// ---------------------------------------------------------------------------
__global__ __launch_bounds__(512) void sample_dw(
    const float* __restrict__ x, const float* __restrict__ offs,
    const unsigned* __restrict__ wdh, unsigned* __restrict__ dwp) {
  int blk = blockIdx.x;
  int csplit = blk & 7;
  int rowtile = (blk >> 3) & 7;
  int b = blk >> 6;
  int tid = threadIdx.x;
  int r = tid >> 6;
  int w = tid & 63;
  int h = rowtile * 8 + r;
  int lo = rowtile * 8 - 7;  // window rows [lo, lo+WROWS)

  __shared__ uint2 S[WROWS * 68];  // 11968 B

  for (int i = tid; i < WROWS * 4; i += 512) {
    int rr = i >> 2;
    int p = i & 3;
    int m = (p == 0) ? 0 : 64 + p;
    S[rr * 68 + m] = make_uint2(0u, 0u);
  }

  // per-pixel tap setup (channel-independent); weights kept as half2 pairs
  const float* ob = offs + (size_t)b * OFFC * HW + (size_t)h * W + w;
  int idxA[KK], idxB[KK], gpk[KK];
  __half2 wth[KK][4];
  int okmask = 0;
#pragma unroll
  for (int k = 0; k < KK; ++k) {
    int ki = k / 3, kj = k % 3;
    float oy = ob[(size_t)(2 * k) * HW];
    float ox = ob[(size_t)(2 * k + 1) * HW];
    float py = (float)(h - 1 + ki) + oy;
    float px = (float)(w - 1 + kj) + ox;
    float y0f = floorf(py), x0f = floorf(px);
    float dy = py - y0f, dx = px - x0f;
    int y0 = (int)y0f, x0 = (int)x0f;
    int y1 = y0 + 1, x1 = x0 + 1;
    float vy0 = (y0 >= 0 && y0 < H) ? 1.f : 0.f;
    float vy1 = (y1 >= 0 && y1 < H) ? 1.f : 0.f;
    float vx0 = (x0 >= 0 && x0 < W) ? 1.f : 0.f;
    float vx1 = (x1 >= 0 && x1 < W) ? 1.f : 0.f;
    int y0c = min(max(y0, 0), H - 1);
    int y1c = min(max(y1, 0), H - 1);
    int xc0 = min(max(x0, 0), W - 1);
    int xc1 = min(max(x1, 0), W - 1);
    int xm = min(max(x0, -1), 65) + 1;
    int wy0 = y0c - lo, wy1 = y1c - lo;
    bool ok = ((unsigned)wy0 < WROWS) && ((unsigned)wy1 < WROWS);
    okmask |= ((int)ok) << k;
    idxA[k] = wy0 * 68 + xm;
    idxB[k] = wy1 * 68 + xm;
    gpk[k] = y0c | (y1c << 6) | (xc0 << 12) | (xc1 << 18);
    wth[k][0] = __float2half2_rn((1.f - dy) * (1.f - dx) * vy0 * vx0);
    wth[k][1] = __float2half2_rn((1.f - dy) * dx * vy0 * vx1);
    wth[k][2] = __float2half2_rn(dy * (1.f - dx) * vy1 * vx0);
    wth[k][3] = __float2half2_rn(dy * dx * vy1 * vx1);
  }

  const int c0 = csplit * 24;
  const float* xq0 = x + ((size_t)b * C + c0) * HW;

  for (int q = 0; q < 6; ++q) {
    const float* xq = xq0 + (size_t)(q * 4) * HW;
    __syncthreads();
    // stage 4-channel f16-packed window (coalesced reads, cvt_pkrtz pack)
    for (int i = tid; i < WROWS * 64; i += 512) {
      int rr = i >> 6;
      int col = i & 63;
      int ly = lo + rr;
      uint2 p = make_uint2(0u, 0u);
      if (ly >= 0 && ly < H) {
        const float* xp = xq + (size_t)ly * W + col;
        p.x = h2_bits(__floats2half2_rn(xp[0], xp[HW]));
        p.y = h2_bits(__floats2half2_rn(xp[2 * HW], xp[3 * HW]));
      }
      S[rr * 68 + col + 1] = p;
    }
    __syncthreads();

    int cq = c0 + q * 4;
    int cp0 = cq >> 1;
    __half2 acc01 = __float2half2_rn(0.f);
    __half2 acc23 = __float2half2_rn(0.f);
#pragma unroll
    for (int k = 0; k < KK; ++k) {
      __half2 wd01 = bc_h2(wdh[cp0 * KK + k]);        // block-uniform s_load
      __half2 wd23 = bc_h2(wdh[(cp0 + 1) * KK + k]);
      __half2 t01, t23;
      if (__builtin_expect((okmask >> k) & 1, 1)) {
        uint2 u00 = S[idxA[k]], u01 = S[idxA[k] + 1];
        uint2 u10 = S[idxB[k]], u11 = S[idxB[k] + 1];
        t01 = __hmul2(wth[k][0], bc_h2(u00.x));
        t01 = __hfma2(wth[k][1], bc_h2(u01.x), t01);
        t01 = __hfma2(wth[k][2], bc_h2(u10.x), t01);
        t01 = __hfma2(wth[k][3], bc_h2(u11.x), t01);
        t23 = __hmul2(wth[k][0], bc_h2(u00.y));
        t23 = __hfma2(wth[k][1], bc_h2(u01.y), t23);
        t23 = __hfma2(wth[k][2], bc_h2(u10.y), t23);
        t23 = __hfma2(wth[k][3], bc_h2(u11.y), t23);
      } else {  // out-of-window fallback: direct global gather (f32)
        float w0 = __low2float(wth[k][0]), w1 = __low2float(wth[k][1]);
        float w2 = __low2float(wth[k][2]), w3 = __low2float(wth[k][3]);
        int g = gpk[k];
        int a00 = (g & 63) * W + ((g >> 12) & 63);
        int a01 = (g & 63) * W + ((g >> 18) & 63);
        int a10 = ((g >> 6) & 63) * W + ((g >> 12) & 63);
        int a11 = ((g >> 6) & 63) * W + ((g >> 18) & 63);
        const float* p0 = xq;
        const float* p1 = xq + HW;
        const float* p2 = xq + 2 * HW;
        const float* p3 = xq + 3 * HW;
        float t0 = fmaf(w3, p0[a11], fmaf(w2, p0[a10], fmaf(w1, p0[a01], w0 * p0[a00])));
        float t1 = fmaf(w3, p1[a11], fmaf(w2, p1[a10], fmaf(w1, p1[a01], w0 * p1[a00])));
        float t2 = fmaf(w3, p2[a11], fmaf(w2, p2[a10], fmaf(w1, p2[a01], w0 * p2[a00])));
        float t3 = fmaf(w3, p3[a11], fmaf(w2, p3[a10], fmaf(w1, p3[a01], w0 * p3[a00])));
        t01 = __floats2half2_rn(t0, t1);
        t23 = __floats2half2_rn(t2, t3);
      }
      acc01 = __hfma2(wd01, t01, acc01);
      acc23 = __hfma2(wd23, t23, acc23);
    }
    size_t obase = ((size_t)b * 96 + cp0) * HW + (size_t)h * W + w;
    dwp[obase] = h2_bits(acc01);
    dwp[obase + HW] = h2_bits(acc23);
  }
}

// ---------------------------------------------------------------------------
// Kernel C: pointwise 1x1 conv via f16 MFMA (same fragment/CD layout as bf16)
// ---------------------------------------------------------------------------
__global__ __launch_bounds__(256) void pointwise_mfma(
    const unsigned* __restrict__ dwp, const unsigned* __restrict__ wPW,
    float* __restrict__ out) {
  int blk = blockIdx.x;
  int nt = blk & 63;
  int mt = (blk >> 6) % 3;
  int b = blk / 192;
  int n0 = nt * 64;
  int m0 = mt * 128;
  int tid = threadIdx.x;
  int lane = tid & 63;
  int wv = tid >> 6;
  int wm = wv >> 1;
  int wn = wv & 1;
  int lpx = lane & 15;
  int lkg = lane >> 4;

  __shared__ __align__(16) unsigned sA[128 * 22];
  __shared__ __align__(16) unsigned sB[64 * 22];

  f32x4 acc[4][2];
#pragma unroll
  for (int mf = 0; mf < 4; ++mf)
#pragma unroll
    for (int nf = 0; nf < 2; ++nf) acc[mf][nf] = (f32x4){0.f, 0.f, 0.f, 0.f};

  const unsigned* dwb = dwp + (size_t)b * 96 * HW + n0;

  for (int chunk = 0; chunk < 6; ++chunk) {
    int kp0 = chunk * 16;
    __syncthreads();
#pragma unroll
    for (int t = 0; t < 8; ++t) {
      int i = t * 256 + tid;
      int m = i >> 4;
      int cd = i & 15;
      sA[m * 22 + cd] = wPW[(size_t)(m0 + m) * 96 + kp0 + cd];
    }
#pragma unroll
    for (int t = 0; t < 4; ++t) {
      int i = t * 256 + tid;
      int kp = i >> 6;
      int px = i & 63;
      sB[px * 22 + kp] = dwb[(size_t)(kp0 + kp) * HW + px];
    }
    __syncthreads();

    half8 af[4];
#pragma unroll
    for (int mf = 0; mf < 4; ++mf) {
      int m = wm * 64 + mf * 16 + lpx;
      af[mf] = ld_frag8h(&sA[m * 22 + lkg * 4]);
    }
    half8 bf[2];
#pragma unroll
    for (int nf = 0; nf < 2; ++nf) {
      int px = wn * 32 + nf * 16 + lpx;
      bf[nf] = ld_frag8h(&sB[px * 22 + lkg * 4]);
    }
#pragma unroll
    for (int mf = 0; mf < 4; ++mf)
#pragma unroll
      for (int nf = 0; nf < 2; ++nf)
        acc[mf][nf] = __builtin_amdgcn_mfma_f32_16x16x32_f16(
            af[mf], bf[nf], acc[mf][nf], 0, 0, 0);
  }

#pragma unroll
  for (int mf = 0; mf < 4; ++mf) {
#pragma unroll
    for (int nf = 0; nf < 2; ++nf) {
      int px = n0 + wn * 32 + nf * 16 + lpx;
#pragma unroll
      for (int j = 0; j < 4; ++j) {
        int o = m0 + wm * 64 + mf * 16 + lkg * 4 + j;
        out[((size_t)b * COUT + o) * HW + px] = acc[mf][nf][j];
      }
    }
  }
}

// ---------------------------------------------------------------------------
extern "C" void kernel_launch(void* const* d_in, const int* in_sizes, int n_in,
                              void* d_out, int out_size, void* d_ws,
                              size_t ws_size, hipStream_t stream) {
  const float* x = (const float*)d_in[0];
  const float* w_off = (const float*)d_in[1];
  const float* b_off = (const float*)d_in[2];
  const float* w_dw = (const float*)d_in[3];
  const float* w_pw = (const float*)d_in[4];
  float* out = (float*)d_out;

  char* ws = (char*)d_ws;
  float* offs = (float*)ws;                       // 4.72 MB
  unsigned* dwp = (unsigned*)(ws + 4718592);      // 25.17 MB
  unsigned short* wA = (unsigned short*)(ws + 4718592 + 25165824);       // 110 KB
  unsigned* wPW = (unsigned*)(ws + 4718592 + 25165824 + 110592);         // 147 KB
  unsigned* wdh = (unsigned*)(ws + 4718592 + 25165824 + 110592 + 147456);// 3.5 KB

  hipMemsetAsync(offs, 0, (size_t)BB * OFFC * HW * sizeof(float), stream);
  int prep_n = 9 * 32 * C + COUT * (C / 2) + (C / 2) * KK;
  prep_weights<<<(prep_n + 255) / 256, 256, 0, stream>>>(w_off, w_pw, w_dw, wA,
                                                         wPW, wdh);
  offset_mfma<<<BB * 16 * 6, 256, 0, stream>>>(x, wA, b_off, offs);
  sample_dw<<<BB * 8 * 8, 512, 0, stream>>>(x, offs, wdh, dwp);
  pointwise_mfma<<<BB * 3 * 64, 256, 0, stream>>>(dwp, wPW, out);
}

// Round 11
// 128.993 us; speedup vs baseline: 1.6622x; 1.1836x over previous
//
#include <hip/hip_runtime.h>
#include <hip/hip_fp16.h>

#define BB 16
#define C 192
#define COUT 384
#define H 64
#define W 64
#define HW (H * W)
#define KK 9
#define OFFC 18
#define WROWS 18  // sample_dw staged window rows: [h0-7, h0+11)

typedef __attribute__((ext_vector_type(8))) short short8;
typedef __attribute__((ext_vector_type(8))) _Float16 half8;
typedef __attribute__((ext_vector_type(4))) float f32x4;

// round-to-nearest-even f32 -> bf16 bits
static __device__ inline unsigned short f2bf(float f) {
  union { float f; unsigned u; } v;
  v.f = f;
  unsigned r = v.u + 0x7FFF + ((v.u >> 16) & 1);
  return (unsigned short)(r >> 16);
}

union H2U { __half2 h; unsigned u; };

static __device__ inline __half2 bc_h2(unsigned u) {
  H2U v; v.u = u; return v.h;
}
static __device__ inline unsigned h2_bits(__half2 h) {
  H2U v; v.h = h; return v.u;
}

static __device__ inline short8 ld_frag8(const unsigned* p) {
  union { unsigned u[4]; short8 s; } v;
  uint2 a = *(const uint2*)p;
  uint2 b = *(const uint2*)(p + 2);
  v.u[0] = a.x; v.u[1] = a.y; v.u[2] = b.x; v.u[3] = b.y;
  return v.s;
}
static __device__ inline half8 ld_frag8h(const unsigned* p) {
  union { unsigned u[4]; half8 s; } v;
  uint2 a = *(const uint2*)p;
  uint2 b = *(const uint2*)(p + 2);
  v.u[0] = a.x; v.u[1] = a.y; v.u[2] = b.x; v.u[3] = b.y;
  return v.s;
}

// ---------------------------------------------------------------------------
// Merged prep: wA (bf16, offset conv) + wPW (f16 c-pairs) + wdh (f16 dw pairs)
// ---------------------------------------------------------------------------
__global__ __launch_bounds__(256) void prep_weights(
    const float* __restrict__ w_off, const float* __restrict__ w_pw,
    const float* __restrict__ w_dw, unsigned short* __restrict__ wA,
    unsigned* __restrict__ wPW, unsigned* __restrict__ wdh) {
  int idx = blockIdx.x * 256 + threadIdx.x;
  if (idx < 9 * 32 * C) {
    int k = idx / (32 * C);
    int rem = idx % (32 * C);
    int o = rem / C;
    int c = rem % C;
    float v = (o < OFFC) ? w_off[((size_t)o * C + c) * KK + k] : 0.f;
    wA[idx] = f2bf(v);
    return;
  }
  int i2 = idx - 9 * 32 * C;
  if (i2 < COUT * (C / 2)) {
    float2 v = *(const float2*)(w_pw + (size_t)i2 * 2);
    wPW[i2] = h2_bits(__floats2half2_rn(v.x, v.y));
    return;
  }
  int i3 = i2 - COUT * (C / 2);
  if (i3 < (C / 2) * KK) {
    int cp = i3 / KK;
    int k = i3 % KK;
    wdh[i3] = h2_bits(
        __floats2half2_rn(w_dw[(size_t)(2 * cp) * KK + k],
                          w_dw[(size_t)(2 * cp + 1) * KK + k]));
  }
}

// ---------------------------------------------------------------------------
// Kernel A: offset conv via bf16 MFMA, K-split over 6 chunk-blocks [unchanged]
// ---------------------------------------------------------------------------
__global__ __launch_bounds__(256) void offset_mfma(
    const float* __restrict__ x, const unsigned short* __restrict__ wA,
    const float* __restrict__ b_off, float* __restrict__ offs) {
  int blk = blockIdx.x;
  int chunk = blk % 6;
  int stripe = (blk / 6) & 15;
  int b = blk / 96;
  int h0 = stripe * 4;
  int c0 = chunk * 32;
  int tid = threadIdx.x;
  int lane = tid & 63;
  int wv = tid >> 6;
  int lpx = lane & 15;
  int lkg = lane >> 4;

  __shared__ __align__(16) unsigned short xlds[6 * 68 * 40];  // 32640 B

  for (int i = tid; i < 6 * 2 * 16; i += 256) {
    int rr = i >> 5;
    int side = (i >> 4) & 1;
    int cd = i & 15;
    int m = side ? 65 : 0;
    ((unsigned*)xlds)[(rr * 68 + m) * 20 + cd] = 0u;
  }

  const float* xb = x + (size_t)b * C * HW;
#pragma unroll
  for (int t = 0; t < 24; ++t) {
    int i = t * 256 + tid;
    int cc2 = i / 384;
    int rem = i % 384;
    int rr = rem >> 6;
    int col = rem & 63;
    int ly = h0 + rr - 1;
    float a0 = 0.f, a1 = 0.f;
    if (ly >= 0 && ly < H) {
      const float* xp = xb + (size_t)(c0 + 2 * cc2) * HW + ly * W + col;
      a0 = xp[0];
      a1 = xp[HW];
    }
    unsigned pack = ((unsigned)f2bf(a1) << 16) | (unsigned)f2bf(a0);
    ((unsigned*)xlds)[(rr * 68 + col + 1) * 20 + cc2] = pack;
  }

  short8 af[9][2];
#pragma unroll
  for (int k = 0; k < 9; ++k)
#pragma unroll
    for (int m = 0; m < 2; ++m)
      af[k][m] = *(const short8*)(wA + (size_t)(k * 32 + m * 16 + lpx) * C +
                                  c0 + lkg * 8);

  f32x4 acc[4][2];
#pragma unroll
  for (int nt = 0; nt < 4; ++nt)
#pragma unroll
    for (int m = 0; m < 2; ++m) acc[nt][m] = (f32x4){0.f, 0.f, 0.f, 0.f};

  __syncthreads();

#pragma unroll
  for (int nt = 0; nt < 4; ++nt) {
#pragma unroll
    for (int k = 0; k < 9; ++k) {
      int ki = k / 3, kj = k % 3;
      short8 bf =
          *(const short8*)&xlds[((wv + ki) * 68 + nt * 16 + lpx + kj) * 40 +
                                lkg * 8];
      acc[nt][0] = __builtin_amdgcn_mfma_f32_16x16x32_bf16(af[k][0], bf,
                                                           acc[nt][0], 0, 0, 0);
      acc[nt][1] = __builtin_amdgcn_mfma_f32_16x16x32_bf16(af[k][1], bf,
                                                           acc[nt][1], 0, 0, 0);
    }
  }

  int h = h0 + wv;
#pragma unroll
  for (int nt = 0; nt < 4; ++nt) {
    int col = nt * 16 + lpx;
#pragma unroll
    for (int j = 0; j < 4; ++j) {
      int o = lkg * 4 + j;
      float v = acc[nt][0][j] + ((chunk == 0) ? b_off[o] : 0.f);
      atomicAdd(&offs[((size_t)b * OFFC + o) * HW + h * W + col], v);
    }
    if (lkg == 0) {
#pragma unroll
      for (int j = 0; j < 2; ++j) {
        int o2 = 16 + j;
        float v = acc[nt][1][j] + ((chunk == 0) ? b_off[o2] : 0.f);
        atomicAdd(&offs[((size_t)b * OFFC + o2) * HW + h * W + col], v);
      }
    }
  }
}

// ---------------------------------------------------------------------------
// Kernel B: bilinear sample + depthwise -> dwp[B][96][HW] packed f16 c-pairs
// 256 thr = 4 rows x 64 cols, 8-way csplit, grid = B*16*8 = 2048 blocks.
// Branch-free hot loop: window-clamped LDS taps, packed tap state
// (idx pair in one int, weights as 2 x half2). Rare out-of-window pixels
// (okmask != 0x1FF, ~12 sigma) fixed up post-hoc from global f32.
// ---------------------------------------------------------------------------
__global__ __launch_bounds__(256) void sample_dw(
    const float* __restrict__ x, const float* __restrict__ offs,
    const unsigned* __restrict__ wdh, unsigned* __restrict__ dwp) {
  int blk = blockIdx.x;
  int csplit = blk & 7;
  int rowtile = (blk >> 3) & 15;
  int b = blk >> 7;
  int tid = threadIdx.x;
  int r = tid >> 6;
  int w = tid & 63;
  int h0 = rowtile * 4;
  int h = h0 + r;
  int lo = h0 - 7;  // window rows [lo, lo+WROWS)

  __shared__ uint2 S[WROWS * 68];  // 9792 B

  // zero pad columns m in {0,65,66,67} (staging writes 1..64 only)
  for (int i = tid; i < WROWS * 4; i += 256) {
    int rr = i >> 2;
    int p = i & 3;
    int m = (p == 0) ? 0 : 64 + p;
    S[rr * 68 + m] = make_uint2(0u, 0u);
  }

  // per-pixel tap setup (channel-independent), packed state
  const float* ob = offs + (size_t)b * OFFC * HW + (size_t)h * W + w;
  int idxAB[KK];
  __half2 w01[KK], w23[KK];
  int okmask = 0;
#pragma unroll
  for (int k = 0; k < KK; ++k) {
    int ki = k / 3, kj = k % 3;
    float oy = ob[(size_t)(2 * k) * HW];
    float ox = ob[(size_t)(2 * k + 1) * HW];
    float py = (float)(h - 1 + ki) + oy;
    float px = (float)(w - 1 + kj) + ox;
    float y0f = floorf(py), x0f = floorf(px);
    float dy = py - y0f, dx = px - x0f;
    int y0 = (int)y0f, x0 = (int)x0f;
    int y1 = y0 + 1, x1 = x0 + 1;
    float vy0 = (y0 >= 0 && y0 < H) ? 1.f : 0.f;
    float vy1 = (y1 >= 0 && y1 < H) ? 1.f : 0.f;
    float vx0 = (x0 >= 0 && x0 < W) ? 1.f : 0.f;
    float vx1 = (x1 >= 0 && x1 < W) ? 1.f : 0.f;
    int y0c = min(max(y0, 0), H - 1);
    int y1c = min(max(y1, 0), H - 1);
    int xm = min(max(x0, -1), 65) + 1;  // plane cols (xm, xm+1)
    int wy0 = y0c - lo, wy1 = y1c - lo;
    bool ok = ((unsigned)wy0 < WROWS) && ((unsigned)wy1 < WROWS);
    okmask |= ((int)ok) << k;
    int wy0c = min(max(wy0, 0), WROWS - 1);
    int wy1c = min(max(wy1, 0), WROWS - 1);
    idxAB[k] = (wy0c * 68 + xm) | ((wy1c * 68 + xm) << 16);
    w01[k] = __floats2half2_rn((1.f - dy) * (1.f - dx) * vy0 * vx0,
                               (1.f - dy) * dx * vy0 * vx1);
    w23[k] = __floats2half2_rn(dy * (1.f - dx) * vy1 * vx0,
                               dy * dx * vy1 * vx1);
  }

  const int c0 = csplit * 24;
  const float* xq0 = x + ((size_t)b * C + c0) * HW;

  for (int q = 0; q < 6; ++q) {
    const float* xq = xq0 + (size_t)(q * 4) * HW;
    __syncthreads();
    // stage 4-channel f16-packed window (coalesced)
    for (int i = tid; i < WROWS * 64; i += 256) {
      int rr = i >> 6;
      int col = i & 63;
      int ly = lo + rr;
      uint2 p = make_uint2(0u, 0u);
      if (ly >= 0 && ly < H) {
        const float* xp = xq + (size_t)ly * W + col;
        p.x = h2_bits(__floats2half2_rn(xp[0], xp[HW]));
        p.y = h2_bits(__floats2half2_rn(xp[2 * HW], xp[3 * HW]));
      }
      S[rr * 68 + col + 1] = p;
    }
    __syncthreads();

    int cp0 = (c0 + q * 4) >> 1;
    __half2 acc01 = __float2half2_rn(0.f);
    __half2 acc23 = __float2half2_rn(0.f);
#pragma unroll
    for (int k = 0; k < KK; ++k) {
      int ia = idxAB[k] & 0xFFFF;
      int ib = idxAB[k] >> 16;
      uint2 u00 = S[ia], u01 = S[ia + 1];
      uint2 u10 = S[ib], u11 = S[ib + 1];
      __half2 b0 = __half2half2(__low2half(w01[k]));
      __half2 b1 = __half2half2(__high2half(w01[k]));
      __half2 b2 = __half2half2(__low2half(w23[k]));
      __half2 b3 = __half2half2(__high2half(w23[k]));
      __half2 t01 = __hmul2(b0, bc_h2(u00.x));
      t01 = __hfma2(b1, bc_h2(u01.x), t01);
      t01 = __hfma2(b2, bc_h2(u10.x), t01);
      t01 = __hfma2(b3, bc_h2(u11.x), t01);
      __half2 t23 = __hmul2(b0, bc_h2(u00.y));
      t23 = __hfma2(b1, bc_h2(u01.y), t23);
      t23 = __hfma2(b2, bc_h2(u10.y), t23);
      t23 = __hfma2(b3, bc_h2(u11.y), t23);
      acc01 = __hfma2(bc_h2(wdh[cp0 * KK + k]), t01, acc01);
      acc23 = __hfma2(bc_h2(wdh[(cp0 + 1) * KK + k]), t23, acc23);
    }
    size_t obase = ((size_t)b * 96 + cp0) * HW + (size_t)h * W + w;
    dwp[obase] = h2_bits(acc01);
    dwp[obase + HW] = h2_bits(acc23);
  }

  // cold fixup: any tap outside the staged window -> exact recompute (global)
  if (__builtin_expect(okmask != 0x1FF, 0)) {
#pragma unroll 1
    for (int q = 0; q < 6; ++q) {
      int cq = c0 + q * 4;
      int cp0 = cq >> 1;
      const float* xq = xq0 + (size_t)(q * 4) * HW;
      float a0 = 0.f, a1 = 0.f, a2 = 0.f, a3 = 0.f;
#pragma unroll 1
      for (int k = 0; k < KK; ++k) {
        int ki = k / 3, kj = k % 3;
        float oy = ob[(size_t)(2 * k) * HW];
        float ox = ob[(size_t)(2 * k + 1) * HW];
        float py = (float)(h - 1 + ki) + oy;
        float px = (float)(w - 1 + kj) + ox;
        float y0f = floorf(py), x0f = floorf(px);
        float dy = py - y0f, dx = px - x0f;
        int y0 = (int)y0f, x0 = (int)x0f;
        int y1 = y0 + 1, x1 = x0 + 1;
        float vy0 = (y0 >= 0 && y0 < H) ? 1.f : 0.f;
        float vy1 = (y1 >= 0 && y1 < H) ? 1.f : 0.f;
        float vx0 = (x0 >= 0 && x0 < W) ? 1.f : 0.f;
        float vx1 = (x1 >= 0 && x1 < W) ? 1.f : 0.f;
        int y0c = min(max(y0, 0), H - 1);
        int y1c = min(max(y1, 0), H - 1);
        int xc0 = min(max(x0, 0), W - 1);
        int xc1 = min(max(x1, 0), W - 1);
        float w0 = (1.f - dy) * (1.f - dx) * vy0 * vx0;
        float w1 = (1.f - dy) * dx * vy0 * vx1;
        float w2 = dy * (1.f - dx) * vy1 * vx0;
        float w3 = dy * dx * vy1 * vx1;
        int a00 = y0c * W + xc0, a01 = y0c * W + xc1;
        int a10 = y1c * W + xc0, a11 = y1c * W + xc1;
        __half2 wd01 = bc_h2(wdh[cp0 * KK + k]);
        __half2 wd23 = bc_h2(wdh[(cp0 + 1) * KK + k]);
        const float* p0 = xq;
        const float* p1 = xq + HW;
        const float* p2 = xq + 2 * HW;
        const float* p3 = xq + 3 * HW;
        float t0 = fmaf(w3, p0[a11], fmaf(w2, p0[a10], fmaf(w1, p0[a01], w0 * p0[a00])));
        float t1 = fmaf(w3, p1[a11], fmaf(w2, p1[a10], fmaf(w1, p1[a01], w0 * p1[a00])));
        float t2 = fmaf(w3, p2[a11], fmaf(w2, p2[a10], fmaf(w1, p2[a01], w0 * p2[a00])));
        float t3 = fmaf(w3, p3[a11], fmaf(w2, p3[a10], fmaf(w1, p3[a01], w0 * p3[a00])));
        a0 = fmaf(__low2float(wd01), t0, a0);
        a1 = fmaf(__high2float(wd01), t1, a1);
        a2 = fmaf(__low2float(wd23), t2, a2);
        a3 = fmaf(__high2float(wd23), t3, a3);
      }
      size_t obase = ((size_t)b * 96 + cp0) * HW + (size_t)h * W + w;
      dwp[obase] = h2_bits(__floats2half2_rn(a0, a1));
      dwp[obase + HW] = h2_bits(__floats2half2_rn(a2, a3));
    }
  }
}

// ---------------------------------------------------------------------------
// Kernel C: pointwise 1x1 conv via f16 MFMA  [unchanged]
// ---------------------------------------------------------------------------
__global__ __launch_bounds__(256) void pointwise_mfma(
    const unsigned* __restrict__ dwp, const unsigned* __restrict__ wPW,
    float* __restrict__ out) {
  int blk = blockIdx.x;
  int nt = blk & 63;
  int mt = (blk >> 6) % 3;
  int b = blk / 192;
  int n0 = nt * 64;
  int m0 = mt * 128;
  int tid = threadIdx.x;
  int lane = tid & 63;
  int wv = tid >> 6;
  int wm = wv >> 1;
  int wn = wv & 1;
  int lpx = lane & 15;
  int lkg = lane >> 4;

  __shared__ __align__(16) unsigned sA[128 * 22];
  __shared__ __align__(16) unsigned sB[64 * 22];

  f32x4 acc[4][2];
#pragma unroll
  for (int mf = 0; mf < 4; ++mf)
#pragma unroll
    for (int nf = 0; nf < 2; ++nf) acc[mf][nf] = (f32x4){0.f, 0.f, 0.f, 0.f};

  const unsigned* dwb = dwp + (size_t)b * 96 * HW + n0;

  for (int chunk = 0; chunk < 6; ++chunk) {
    int kp0 = chunk * 16;
    __syncthreads();
#pragma unroll
    for (int t = 0; t < 8; ++t) {
      int i = t * 256 + tid;
      int m = i >> 4;
      int cd = i & 15;
      sA[m * 22 + cd] = wPW[(size_t)(m0 + m) * 96 + kp0 + cd];
    }
#pragma unroll
    for (int t = 0; t < 4; ++t) {
      int i = t * 256 + tid;
      int kp = i >> 6;
      int px = i & 63;
      sB[px * 22 + kp] = dwb[(size_t)(kp0 + kp) * HW + px];
    }
    __syncthreads();

    half8 af[4];
#pragma unroll
    for (int mf = 0; mf < 4; ++mf) {
      int m = wm * 64 + mf * 16 + lpx;
      af[mf] = ld_frag8h(&sA[m * 22 + lkg * 4]);
    }
    half8 bf[2];
#pragma unroll
    for (int nf = 0; nf < 2; ++nf) {
      int px = wn * 32 + nf * 16 + lpx;
      bf[nf] = ld_frag8h(&sB[px * 22 + lkg * 4]);
    }
#pragma unroll
    for (int mf = 0; mf < 4; ++mf)
#pragma unroll
      for (int nf = 0; nf < 2; ++nf)
        acc[mf][nf] = __builtin_amdgcn_mfma_f32_16x16x32_f16(
            af[mf], bf[nf], acc[mf][nf], 0, 0, 0);
  }

#pragma unroll
  for (int mf = 0; mf < 4; ++mf) {
#pragma unroll
    for (int nf = 0; nf < 2; ++nf) {
      int px = n0 + wn * 32 + nf * 16 + lpx;
#pragma unroll
      for (int j = 0; j < 4; ++j) {
        int o = m0 + wm * 64 + mf * 16 + lkg * 4 + j;
        out[((size_t)b * COUT + o) * HW + px] = acc[mf][nf][j];
      }
    }
  }
}

// ---------------------------------------------------------------------------
extern "C" void kernel_launch(void* const* d_in, const int* in_sizes, int n_in,
                              void* d_out, int out_size, void* d_ws,
                              size_t ws_size, hipStream_t stream) {
  const float* x = (const float*)d_in[0];
  const float* w_off = (const float*)d_in[1];
  const float* b_off = (const float*)d_in[2];
  const float* w_dw = (const float*)d_in[3];
  const float* w_pw = (const float*)d_in[4];
  float* out = (float*)d_out;

  char* ws = (char*)d_ws;
  float* offs = (float*)ws;                       // 4.72 MB
  unsigned* dwp = (unsigned*)(ws + 4718592);      // 25.17 MB
  unsigned short* wA = (unsigned short*)(ws + 4718592 + 25165824);       // 110 KB
  unsigned* wPW = (unsigned*)(ws + 4718592 + 25165824 + 110592);         // 147 KB
  unsigned* wdh = (unsigned*)(ws + 4718592 + 25165824 + 110592 + 147456);// 3.5 KB

  hipMemsetAsync(offs, 0, (size_t)BB * OFFC * HW * sizeof(float), stream);
  int prep_n = 9 * 32 * C + COUT * (C / 2) + (C / 2) * KK;
  prep_weights<<<(prep_n + 255) / 256, 256, 0, stream>>>(w_off, w_pw, w_dw, wA,
                                                         wPW, wdh);
  offset_mfma<<<BB * 16 * 6, 256, 0, stream>>>(x, wA, b_off, offs);
  sample_dw<<<BB * 16 * 8, 256, 0, stream>>>(x, offs, wdh, dwp);
  pointwise_mfma<<<BB * 3 * 64, 256, 0, stream>>>(dwp, wPW, out);
}